// Round 4
// baseline (256.654 us; speedup 1.0000x reference)
//
#include <hip/hip_runtime.h>

// CapsuleLayer dynamic routing, MI355X. R7: 8-batch-per-wave sweep.
//  - R3..R6 all bound by the per-k chain: 2x ds_read_b128 -> lgkmcnt -> 32 FMA
//    (64 VALU cyc) vs ~120cyc LDS latency: no slack at 2 waves/SIMD.
//  - This version: each wave owns 8 b's (4 waves x 8 = all 32 b per block).
//    Per k: same 2 ds_read_b128 now feed 64 FMA (256 cyc across 2 waves/SIMD)
//    -> LDS latency fully hidden, LDS-read instr count halved
//    (12.3k cyc/CU/sweep < VALU 16.4k -> VALU/HBM-bound, not LDS).
//  - Grid: NG=512 i-groups of IC=4 (keeps 2 blocks/CU). Partial = 33.5MB.
//  - PASS2 VGPR trick: logits2 = V.a0 + V.a1 = V.(a0+a1) -> load as=a0+a1,
//    one 64-reg array instead of two (fits 256-VGPR/2-wave budget).
//  - W staging: R5's global_load_lds dwordx4 dbuf with pre-swizzled source
//    addresses (slot s <-> float4 f bit-permutation), one barrier per ii.
//
// Lane layout: lane l owns d = l>>1, h = l&1, outputs o = d*16 + h*8 + j
// (j=0..7).  a-half combine: shfl_xor(.,1); softmax over D: shfl_xor
// {2,4,8,16,32}.  x loaded as wave-uniform float4 scalar loads, 4-k chunks.

#define B_  32
#define I_  2048
#define K_  16
#define O_  512
#define NG_ 512   // i-groups (partial-buffer leading dim)
#define IC_ 4     // i's per group

#define GLB(p)  ((const __attribute__((address_space(1))) void*)(p))
#define LDSP(p) ((__attribute__((address_space(3))) void*)(p))

template<int PASS>
__global__ __launch_bounds__(256, 2)
void sweep_kernel(const float* __restrict__ x, const float* __restrict__ W,
                  const float* __restrict__ act0_g, const float* __restrict__ act1_g,
                  float* __restrict__ partial)
{
    const int tid  = threadIdx.x;
    const int lane = tid & 63;
    const int wave = tid >> 6;              // 0..3
    const int ig   = blockIdx.x;            // 0..511
    const int d    = lane >> 1;             // 0..31
    const int h    = lane & 1;
    const int obase = d * 16 + h * 8;       // lane's first o

    // wave-uniform batch base (forces SGPR so x loads go scalar)
    const int wv    = __builtin_amdgcn_readfirstlane(wave);
    const int bbase = wv * 8;               // 4 waves x 8 b = 32 b

    __shared__ float sW[2][K_ * O_];        // 2 x 32 KB, permuted W[i] tiles

    // per-lane pre-swizzled source byte offsets: slot s -> global float4 f
    // s = 1024*jq + 64*k + (2*dd+hh); f = k*128 + dd*4 + hh*2 + jq
    int voff[8];
    #pragma unroll
    for (int c = 0; c < 8; ++c) {
        const int s = c * 256 + wave * 64 + lane;       // 16B slot index
        const int f = ((s >> 10) & 1) | ((s & 1) << 1)
                    | (((s >> 1) & 31) << 2) | (((s >> 6) & 15) << 7);
        voff[c] = f << 4;                               // byte offset
    }

    float facc[8][8];
    #pragma unroll
    for (int bb = 0; bb < 8; ++bb)
        #pragma unroll
        for (int j = 0; j < 8; ++j) facc[bb][j] = 0.f;

    // as_ = a0 (PASS1) or a0+a1 (PASS2): logits2 = V.(a0+a1)
    float as_[8][8];
    if (PASS >= 1) {
        #pragma unroll
        for (int bb = 0; bb < 8; ++bb) {
            const float4* p = (const float4*)(act0_g + (bbase + bb) * O_ + obase);
            float4 f0 = p[0], f1 = p[1];
            as_[bb][0]=f0.x; as_[bb][1]=f0.y; as_[bb][2]=f0.z; as_[bb][3]=f0.w;
            as_[bb][4]=f1.x; as_[bb][5]=f1.y; as_[bb][6]=f1.z; as_[bb][7]=f1.w;
            if (PASS == 2) {
                const float4* q = (const float4*)(act1_g + (bbase + bb) * O_ + obase);
                float4 g0 = q[0], g1 = q[1];
                as_[bb][0]+=g0.x; as_[bb][1]+=g0.y; as_[bb][2]+=g0.z; as_[bb][3]+=g0.w;
                as_[bb][4]+=g1.x; as_[bb][5]+=g1.y; as_[bb][6]+=g1.z; as_[bb][7]+=g1.w;
            }
        }
    }

    // prologue: stage W[i0] into buf 0
    {
        const char* gb = (const char*)(W + (size_t)(ig * IC_) * (K_ * O_));
        #pragma unroll
        for (int c = 0; c < 8; ++c)
            __builtin_amdgcn_global_load_lds(GLB(gb + voff[c]),
                LDSP(&sW[0][(c * 256 + wave * 64) * 4]), 16, 0, 0);
    }

    #pragma unroll 1
    for (int ii = 0; ii < IC_; ++ii) {
        const int i = ig * IC_ + ii;
        // implicit vmcnt(0)+barrier: buf[ii&1] staged, prior reads done
        __syncthreads();
        if (ii + 1 < IC_) {
            const char* gb = (const char*)(W + (size_t)(i + 1) * (K_ * O_));
            float* nbuf = sW[(ii + 1) & 1];
            #pragma unroll
            for (int c = 0; c < 8; ++c)
                __builtin_amdgcn_global_load_lds(GLB(gb + voff[c]),
                    LDSP(&nbuf[(c * 256 + wave * 64) * 4]), 16, 0, 0);
        }
        const float* cbuf = sW[ii & 1];

        float V[8][8];
        #pragma unroll
        for (int bb = 0; bb < 8; ++bb)
            #pragma unroll
            for (int j = 0; j < 8; ++j) V[bb][j] = 0.f;

        // k in 4 chunks of 4: x as wave-uniform float4 scalar loads (32 SGPRs
        // live per chunk), W via 2 ds_read_b128 per k feeding 64 FMA
        #pragma unroll
        for (int kc = 0; kc < 4; ++kc) {
            float4 xc[8];
            #pragma unroll
            for (int bb = 0; bb < 8; ++bb)
                xc[bb] = *(const float4*)(x + ((size_t)(bbase + bb) * I_ + i) * K_ + kc * 4);
            #pragma unroll
            for (int kq = 0; kq < 4; ++kq) {
                const int k = kc * 4 + kq;
                const float4 w0 = *(const float4*)&cbuf[k * 256 + lane * 4];
                const float4 w1 = *(const float4*)&cbuf[4096 + k * 256 + lane * 4];
                const float w[8] = {w0.x, w0.y, w0.z, w0.w, w1.x, w1.y, w1.z, w1.w};
                #pragma unroll
                for (int bb = 0; bb < 8; ++bb) {
                    const float xb = ((const float*)&xc[bb])[kq];
                    #pragma unroll
                    for (int j = 0; j < 8; ++j) V[bb][j] = fmaf(xb, w[j], V[bb][j]);
                }
            }
        }

        #pragma unroll
        for (int bb = 0; bb < 8; ++bb) {
            if (PASS == 0) {
                #pragma unroll
                for (int j = 0; j < 8; ++j) facc[bb][j] += V[bb][j];
            } else {
                float p0 = 0.f;
                #pragma unroll
                for (int j = 0; j < 8; ++j) p0 = fmaf(V[bb][j], as_[bb][j], p0);
                p0 += __shfl_xor(p0, 1);        // combine the two a-halves
                // softmax over 32 d's (no max-sub: |logits| small, f32-safe)
                const float e = __expf(p0);
                float s = e;
                s += __shfl_xor(s, 2);
                s += __shfl_xor(s, 4);
                s += __shfl_xor(s, 8);
                s += __shfl_xor(s, 16);
                s += __shfl_xor(s, 32);
                const float r = e * __builtin_amdgcn_rcpf(s);
                #pragma unroll
                for (int j = 0; j < 8; ++j)
                    facc[bb][j] = fmaf(r, V[bb][j], facc[bb][j]);
            }
        }
    }

    // flush per-(ig) partials
    #pragma unroll
    for (int bb = 0; bb < 8; ++bb) {
        const int b = bbase + bb;
        float4* dst = (float4*)(partial + ((size_t)ig * B_ + b) * O_ + obase);
        dst[0] = make_float4(facc[bb][0], facc[bb][1], facc[bb][2], facc[bb][3]);
        dst[1] = make_float4(facc[bb][4], facc[bb][5], facc[bb][6], facc[bb][7]);
    }
}

// sum NG_ partials -> *scale + bias -> squash over A -> out
// 512 wgs x 256 thr; wg covers 32 g's; 8 w-slices of 64 reduced via LDS.
__global__ __launch_bounds__(256)
void reduce_squash(const float* __restrict__ partial, const float* __restrict__ bias,
                   float scale, float* __restrict__ out)
{
    const int t  = threadIdx.x;
    const int g  = blockIdx.x * 32 + (t & 31);   // b*512 + o
    const int sl = t >> 5;                       // w-slice 0..7
    float s = 0.f;
    #pragma unroll 8
    for (int w = sl * 64; w < sl * 64 + 64; ++w)
        s += partial[(size_t)w * (B_ * O_) + g];
    __shared__ float red[256];
    red[t] = s;
    __syncthreads();
    if (t < 32) {
        float v = red[t];
        #pragma unroll
        for (int r = 1; r < 8; ++r) v += red[t + 32 * r];
        const float p = fmaf(v, scale, bias[g & (O_ - 1)]);
        float nn = p * p;
        nn += __shfl_xor(nn, 1);
        nn += __shfl_xor(nn, 2);
        nn += __shfl_xor(nn, 4);
        nn += __shfl_xor(nn, 8);
        out[g] = p * sqrtf(nn) / (1.f + nn);
    }
}

extern "C" void kernel_launch(void* const* d_in, const int* in_sizes, int n_in,
                              void* d_out, int out_size, void* d_ws, size_t ws_size,
                              hipStream_t stream) {
    const float* x    = (const float*)d_in[0];   // [32,2048,16]
    const float* W    = (const float*)d_in[1];   // [2048,16,512]
    const float* bias = (const float*)d_in[2];   // [512]
    float* out = (float*)d_out;                  // [32,512]

    float* partial = (float*)d_ws;                       // NG_*32*512 f32 = 33.5 MB
    float* act0    = partial + (size_t)NG_ * B_ * O_;    // 64 KB
    float* act1    = act0 + B_ * O_;                     // 64 KB

    sweep_kernel<0><<<NG_, 256, 0, stream>>>(x, W, nullptr, nullptr, partial);
    reduce_squash<<<512, 256, 0, stream>>>(partial, bias, 1.f / 32.f, act0);
    sweep_kernel<1><<<NG_, 256, 0, stream>>>(x, W, act0, nullptr, partial);
    reduce_squash<<<512, 256, 0, stream>>>(partial, bias, 1.f, act1);
    sweep_kernel<2><<<NG_, 256, 0, stream>>>(x, W, act0, act1, partial);
    reduce_squash<<<512, 256, 0, stream>>>(partial, bias, 1.f, out);
}